// Round 7
// baseline (152.085 us; speedup 1.0000x reference)
//
#include <hip/hip_runtime.h>

#define NB   2
#define NCO  8
#define NCI  8
#define ND   8
#define NGH  16
#define NGW  16
#define NH   512
#define NW   512
#define HW   (NH * NW)
#define COLS 128           // floats per column: 8 co * (8 W + 8 B)
#define TBL  (17 * COLS)   // 17 columns (col 16 zero-padded for the C-read)

// One 256-thread block per (b, row-pair); each thread does 4 consecutive px
// of one row (float4 global I/O). Grid is y-interpolated into a per-row LDS
// table; epilogue reads 3 columns (A,B,C) once per co and combines with
// per-px x-tent weights -> 3 LDS reads/px (was 8), branch-free cell crossing.
__global__ __launch_bounds__(256, 3) void bslice_kernel(
    const float* __restrict__ grid,
    const float* __restrict__ guide,
    const float* __restrict__ inp,
    float* __restrict__ out)
{
    const int tid = threadIdx.x;
    const int b   = blockIdx.y;
    const int y0  = blockIdx.x * 2;
    const int lr  = tid >> 7;            // 0/1: which row of the pair
    const int y   = y0 + lr;
    const int px0 = (tid & 127) << 2;    // 4 px per thread

    const float step = 15.0f / 511.0f;

    // ---- issue the 16 input float4 loads first (HBM latency head start) ----
    const size_t inbase = (size_t)b * NCI * HW + (size_t)y * NW + px0;
    float4 gld[NCI], vld[NCI];
    #pragma unroll
    for (int ci = 0; ci < NCI; ++ci) {
        gld[ci] = *(const float4*)(guide + inbase + (size_t)ci * HW);
        vld[ci] = *(const float4*)(inp   + inbase + (size_t)ci * HW);
    }

    // ---- stage y-interpolated grid tables, one per row ----
    // sg[row][col*128 + co*16 + k*8 + z], bias (k=1) pre-scaled by 1/8.
    __shared__ float sg[2 * TBL];
    float ypf0 = (float)y0 * step;
    float ypf1 = (float)(y0 + 1) * step;
    int   cy0 = min((int)ypf0, NGH - 2), cy1 = min((int)ypf1, NGH - 2);
    float wy0 = ypf0 - (float)cy0,       wy1 = ypf1 - (float)cy1;

    for (int i = tid; i < 2 * TBL; i += 256) {
        int row = (i >= TBL);
        int r   = i - (row ? TBL : 0);
        int col = r >> 7;                // 0..16
        float v = 0.f;
        if (col < 16) {
            int j  = r & 127;
            int co = j >> 4, k = (j >> 3) & 1, z = j & 7;
            int   cy = row ? cy1 : cy0;
            float wy = row ? wy1 : wy0;
            const float* gp = grid
                + ((((size_t)(b * NCO + co) * 2 + k) * ND + z) * NGH + cy) * NGW + col;
            v = gp[0] * (1.f - wy) + gp[NGW] * wy;
            if (k) v *= 0.125f;          // fold bias mean (1/8)
        }
        sg[i] = v;
    }
    __syncthreads();

    // ---- per-px z-tent accumulators from guide/input ----
    float S0[4][8], S1[4][8];
    #pragma unroll
    for (int i = 0; i < 4; ++i)
        #pragma unroll
        for (int z = 0; z < 8; ++z) { S0[i][z] = 0.f; S1[i][z] = 0.f; }

    #pragma unroll
    for (int ci = 0; ci < NCI; ++ci) {
        const float gv[4] = { gld[ci].x, gld[ci].y, gld[ci].z, gld[ci].w };
        const float vv[4] = { vld[ci].x, vld[ci].y, vld[ci].z, vld[ci].w };
        #pragma unroll
        for (int i = 0; i < 4; ++i) {
            float zp = fminf(fmaxf(gv[i] * 7.0f, 0.0f), 7.0f);
            #pragma unroll
            for (int z = 0; z < 8; ++z) {
                float a = fmaxf(0.0f, 1.0f - fabsf(zp - (float)z));
                S0[i][z] = fmaf(a, vv[i], S0[i][z]);
                S1[i][z] += a;
            }
        }
    }

    // ---- x-tent weights over columns c0, c0+1, c0+2 ----
    const float xp0f = (float)px0 * step;
    const int   c0   = min((int)xp0f, NGW - 2);
    float wA[4], wB[4], wC[4];
    #pragma unroll
    for (int i = 0; i < 4; ++i) {
        float u = xp0f + (float)i * step - (float)c0;   // in [0, ~1.12)
        wA[i] = fmaxf(0.0f, 1.0f - u);
        wB[i] = 1.0f - fabsf(u - 1.0f);
        wC[i] = fmaxf(0.0f, u - 1.0f);
    }

    const float* tb = sg + (lr ? TBL : 0) + c0 * COLS;
    const size_t obase = (size_t)b * NCO * HW + (size_t)y * NW + px0;

    #pragma unroll 1
    for (int co = 0; co < NCO; ++co) {
        const float* p = tb + co * 16;
        float acc[4];

        #pragma unroll
        for (int c = 0; c < 3; ++c) {               // columns A, B, C
            const float* q = p + c * COLS;
            const float4 a0 = *(const float4*)(q + 0);
            const float4 a1 = *(const float4*)(q + 4);
            const float4 a2 = *(const float4*)(q + 8);
            const float4 a3 = *(const float4*)(q + 12);
            #pragma unroll
            for (int i = 0; i < 4; ++i) {
                float t;
                t = S0[i][0] * a0.x;
                t = fmaf(S0[i][1], a0.y, t);
                t = fmaf(S0[i][2], a0.z, t);
                t = fmaf(S0[i][3], a0.w, t);
                t = fmaf(S0[i][4], a1.x, t);
                t = fmaf(S0[i][5], a1.y, t);
                t = fmaf(S0[i][6], a1.z, t);
                t = fmaf(S0[i][7], a1.w, t);
                t = fmaf(S1[i][0], a2.x, t);
                t = fmaf(S1[i][1], a2.y, t);
                t = fmaf(S1[i][2], a2.z, t);
                t = fmaf(S1[i][3], a2.w, t);
                t = fmaf(S1[i][4], a3.x, t);
                t = fmaf(S1[i][5], a3.y, t);
                t = fmaf(S1[i][6], a3.z, t);
                t = fmaf(S1[i][7], a3.w, t);
                float w = (c == 0) ? wA[i] : (c == 1) ? wB[i] : wC[i];
                acc[i] = (c == 0) ? w * t : fmaf(w, t, acc[i]);
            }
        }

        *(float4*)(out + obase + (size_t)co * HW) =
            make_float4(acc[0], acc[1], acc[2], acc[3]);
    }
}

extern "C" void kernel_launch(void* const* d_in, const int* in_sizes, int n_in,
                              void* d_out, int out_size, void* d_ws, size_t ws_size,
                              hipStream_t stream) {
    const float* grid  = (const float*)d_in[0];
    const float* guide = (const float*)d_in[1];
    const float* inp   = (const float*)d_in[2];
    float* out = (float*)d_out;

    dim3 g(NH / 2, NB);   // (256 row-pairs, 2 batches) = 512 blocks x 4 waves
    bslice_kernel<<<g, 256, 0, stream>>>(grid, guide, inp, out);
}

// Round 8
// 93.381 us; speedup vs baseline: 1.6287x; 1.6287x over previous
//
#include <hip/hip_runtime.h>

#define NB   2
#define NCO  8
#define NCI  8
#define ND   8
#define NGH  16
#define NGW  16
#define NH   512
#define NW   512
#define HW   (NH * NW)
#define CSTR 132   // LDS column stride in floats: 128 data + 4 pad (4 mod 32 banks -> conflict-free)

// One 256-thread block per (b, row); 2 px/thread (float2 I/O).
// Grid y-interpolated into LDS table sg[col*CSTR + co*16 + k*8 + z] (17 cols,
// col 16 zeroed; bias pre-scaled 1/8). Epilogue: per co, read columns
// c0,c0+1,c0+2 one at a time (peak live ~60 VGPR) and combine with branch-free
// x-tent weights (exact bilinear incl. cell crossing).
__global__ __launch_bounds__(256, 4) void bslice_kernel(
    const float* __restrict__ grid,
    const float* __restrict__ guide,
    const float* __restrict__ inp,
    float* __restrict__ out)
{
    const int tid = threadIdx.x;
    const int y   = blockIdx.x;
    const int b   = blockIdx.y;

    const float step = 15.0f / 511.0f;
    const float yp = (float)y * step;
    const int   cy = min((int)yp, NGH - 2);
    const float wy = yp - (float)cy;

    __shared__ float sg[17 * CSTR];
    if (tid < 128) sg[16 * CSTR + tid] = 0.f;    // zero pad column 16
    for (int i = tid; i < 16 * 128; i += 256) {
        int col = i & 15;                        // gw: fastest -> coalesced grid reads
        int j   = i >> 4;                        // j = co*16 + k*8 + z
        int co  = j >> 4, k = (j >> 3) & 1, z = j & 7;
        const float* gp = grid
            + ((((size_t)(b * NCO + co) * 2 + k) * ND + z) * NGH + cy) * NGW + col;
        float v = gp[0] * (1.f - wy) + gp[NGW] * wy;
        if (k) v *= 0.125f;                      // fold bias mean (1/8)
        sg[col * CSTR + j] = v;
    }
    __syncthreads();

    const int px0 = tid * 2;
    const float xp0 = (float)px0 * step;
    const int   c0  = min((int)xp0, NGW - 2);
    const float u0  = xp0 - (float)c0;           // [0, ~1.03)
    const float u1  = u0 + step;                 // [0, ~1.06)
    // x-tent weights over columns c0, c0+1, c0+2 (exact bilinear, branch-free)
    const float wA0 = fmaxf(0.f, 1.f - u0), wA1 = fmaxf(0.f, 1.f - u1);
    const float wB0 = 1.f - fabsf(u0 - 1.f), wB1 = 1.f - fabsf(u1 - 1.f);
    const float wC0 = fmaxf(0.f, u0 - 1.f), wC1 = fmaxf(0.f, u1 - 1.f);

    // ---- z-tent accumulators for the 2 pixels ----
    float S0[2][8], S1[2][8];
    #pragma unroll
    for (int p = 0; p < 2; ++p)
        #pragma unroll
        for (int z = 0; z < 8; ++z) { S0[p][z] = 0.f; S1[p][z] = 0.f; }

    const size_t inbase = (size_t)b * NCI * HW + (size_t)y * NW + px0;
    #pragma unroll
    for (int ci = 0; ci < NCI; ++ci) {
        const float2 g2 = *(const float2*)(guide + inbase + (size_t)ci * HW);
        const float2 v2 = *(const float2*)(inp   + inbase + (size_t)ci * HW);
        #pragma unroll
        for (int p = 0; p < 2; ++p) {
            float g = p ? g2.y : g2.x;
            float v = p ? v2.y : v2.x;
            float zp = fminf(fmaxf(g * 7.0f, 0.0f), 7.0f);
            #pragma unroll
            for (int z = 0; z < 8; ++z) {
                float a = fmaxf(0.0f, 1.0f - fabsf(zp - (float)z));
                S0[p][z] = fmaf(a, v, S0[p][z]);
                S1[p][z] += a;
            }
        }
    }

    const float* tb = sg + c0 * CSTR;
    const size_t obase = (size_t)b * NCO * HW + (size_t)y * NW + px0;

    #pragma unroll 1
    for (int co = 0; co < NCO; ++co) {
        float dA0, dA1, dB0, dB1, dC0, dC1;
        // one column at a time -> peak live regs small (16 col + 6 dots + 32 S)
        #pragma unroll
        for (int c = 0; c < 3; ++c) {
            const float* q = tb + c * CSTR + co * 16;
            const float4 a0 = *(const float4*)(q + 0);
            const float4 a1 = *(const float4*)(q + 4);
            const float4 a2 = *(const float4*)(q + 8);
            const float4 a3 = *(const float4*)(q + 12);
            float d0, d1;
            d0 = S0[0][0] * a0.x;              d1 = S0[1][0] * a0.x;
            d0 = fmaf(S0[0][1], a0.y, d0);     d1 = fmaf(S0[1][1], a0.y, d1);
            d0 = fmaf(S0[0][2], a0.z, d0);     d1 = fmaf(S0[1][2], a0.z, d1);
            d0 = fmaf(S0[0][3], a0.w, d0);     d1 = fmaf(S0[1][3], a0.w, d1);
            d0 = fmaf(S0[0][4], a1.x, d0);     d1 = fmaf(S0[1][4], a1.x, d1);
            d0 = fmaf(S0[0][5], a1.y, d0);     d1 = fmaf(S0[1][5], a1.y, d1);
            d0 = fmaf(S0[0][6], a1.z, d0);     d1 = fmaf(S0[1][6], a1.z, d1);
            d0 = fmaf(S0[0][7], a1.w, d0);     d1 = fmaf(S0[1][7], a1.w, d1);
            d0 = fmaf(S1[0][0], a2.x, d0);     d1 = fmaf(S1[1][0], a2.x, d1);
            d0 = fmaf(S1[0][1], a2.y, d0);     d1 = fmaf(S1[1][1], a2.y, d1);
            d0 = fmaf(S1[0][2], a2.z, d0);     d1 = fmaf(S1[1][2], a2.z, d1);
            d0 = fmaf(S1[0][3], a2.w, d0);     d1 = fmaf(S1[1][3], a2.w, d1);
            d0 = fmaf(S1[0][4], a3.x, d0);     d1 = fmaf(S1[1][4], a3.x, d1);
            d0 = fmaf(S1[0][5], a3.y, d0);     d1 = fmaf(S1[1][5], a3.y, d1);
            d0 = fmaf(S1[0][6], a3.z, d0);     d1 = fmaf(S1[1][6], a3.z, d1);
            d0 = fmaf(S1[0][7], a3.w, d0);     d1 = fmaf(S1[1][7], a3.w, d1);
            if (c == 0)      { dA0 = d0; dA1 = d1; }
            else if (c == 1) { dB0 = d0; dB1 = d1; }
            else             { dC0 = d0; dC1 = d1; }
        }
        float r0 = wA0 * dA0;
        r0 = fmaf(wB0, dB0, r0);
        r0 = fmaf(wC0, dC0, r0);
        float r1 = wA1 * dA1;
        r1 = fmaf(wB1, dB1, r1);
        r1 = fmaf(wC1, dC1, r1);
        *(float2*)(out + obase + (size_t)co * HW) = make_float2(r0, r1);
    }
}

extern "C" void kernel_launch(void* const* d_in, const int* in_sizes, int n_in,
                              void* d_out, int out_size, void* d_ws, size_t ws_size,
                              hipStream_t stream) {
    const float* grid  = (const float*)d_in[0];
    const float* guide = (const float*)d_in[1];
    const float* inp   = (const float*)d_in[2];
    float* out = (float*)d_out;

    dim3 g(NH, NB);   // (512 rows, 2 batches) = 1024 blocks x 4 waves = 4096 waves
    bslice_kernel<<<g, 256, 0, stream>>>(grid, guide, inp, out);
}

// Round 9
// 91.173 us; speedup vs baseline: 1.6681x; 1.0242x over previous
//
#include <hip/hip_runtime.h>

#define NB   2
#define NCO  8
#define NCI  8
#define ND   8
#define NGH  16
#define NGW  16
#define NH   512
#define NW   512
#define HW   (NH * NW)
#define CSTR 132   // LDS column stride in floats: 128 data + 4 pad (4 mod 32 banks -> conflict-free)

// One 256-thread block per (b, row); 2 px/thread (float2 I/O).
// Phase order puts ALL global loads (grid staging + guide/input) before the
// tent VALU phase, and the barrier directly before the LDS-only epilogue:
//   grid loads -> guide/inp loads -> tent compute -> y-interp+LDS write
//   -> barrier -> 3-column epilogue.
// LDS table sg[col*CSTR + co*16 + k*8 + z], 17 cols (col 16 zeroed),
// bias pre-scaled 1/8. Epilogue: per co read cols c0,c0+1,c0+2 one at a
// time, combine with branch-free x-tent weights (exact bilinear).
__global__ __launch_bounds__(256, 4) void bslice_kernel(
    const float* __restrict__ grid,
    const float* __restrict__ guide,
    const float* __restrict__ inp,
    float* __restrict__ out)
{
    const int tid = threadIdx.x;
    const int y   = blockIdx.x;
    const int b   = blockIdx.y;

    const float step = 15.0f / 511.0f;
    const float yp = (float)y * step;
    const int   cy = min((int)yp, NGH - 2);
    const float wy = yp - (float)cy;

    __shared__ float sg[17 * CSTR];

    // ---- phase 1: issue grid staging loads (8 pairs per thread) ----
    float ga[8], gb[8];
    #pragma unroll
    for (int it = 0; it < 8; ++it) {
        int i   = tid + it * 256;        // 0..2047
        int col = i & 15;
        int j   = i >> 4;                // co*16 + k*8 + z
        int co  = j >> 4, k = (j >> 3) & 1, z = j & 7;
        const float* gp = grid
            + ((((size_t)(b * NCO + co) * 2 + k) * ND + z) * NGH + cy) * NGW + col;
        ga[it] = gp[0];
        gb[it] = gp[NGW];
    }

    // ---- phase 2: issue all guide/input loads (float2, coalesced) ----
    const int px0 = tid * 2;
    const size_t inbase = (size_t)b * NCI * HW + (size_t)y * NW + px0;
    float2 g2[NCI], v2[NCI];
    #pragma unroll
    for (int ci = 0; ci < NCI; ++ci) {
        g2[ci] = *(const float2*)(guide + inbase + (size_t)ci * HW);
        v2[ci] = *(const float2*)(inp   + inbase + (size_t)ci * HW);
    }

    // ---- phase 3: tent accumulation (grid loads still in flight) ----
    float S0[2][8], S1[2][8];
    #pragma unroll
    for (int p = 0; p < 2; ++p)
        #pragma unroll
        for (int z = 0; z < 8; ++z) { S0[p][z] = 0.f; S1[p][z] = 0.f; }

    #pragma unroll
    for (int ci = 0; ci < NCI; ++ci) {
        #pragma unroll
        for (int p = 0; p < 2; ++p) {
            float g = p ? g2[ci].y : g2[ci].x;
            float v = p ? v2[ci].y : v2[ci].x;
            float zp = fminf(fmaxf(g * 7.0f, 0.0f), 7.0f);
            #pragma unroll
            for (int z = 0; z < 8; ++z) {
                float a = fmaxf(0.0f, 1.0f - fabsf(zp - (float)z));
                S0[p][z] = fmaf(a, v, S0[p][z]);
                S1[p][z] += a;
            }
        }
    }

    // ---- phase 4: y-interp + LDS writes, zero pad column 16, barrier ----
    if (tid < 128) sg[16 * CSTR + tid] = 0.f;
    #pragma unroll
    for (int it = 0; it < 8; ++it) {
        int i   = tid + it * 256;
        int col = i & 15;
        int j   = i >> 4;
        int k   = (j >> 3) & 1;
        float v = ga[it] * (1.f - wy) + gb[it] * wy;
        if (k) v *= 0.125f;              // fold bias mean (1/8)
        sg[col * CSTR + j] = v;
    }
    __syncthreads();

    // ---- phase 5: epilogue ----
    const float xp0 = (float)px0 * step;
    const int   c0  = min((int)xp0, NGW - 2);
    const float u0  = xp0 - (float)c0;
    const float u1  = u0 + step;
    const float wA0 = fmaxf(0.f, 1.f - u0), wA1 = fmaxf(0.f, 1.f - u1);
    const float wB0 = 1.f - fabsf(u0 - 1.f), wB1 = 1.f - fabsf(u1 - 1.f);
    const float wC0 = fmaxf(0.f, u0 - 1.f), wC1 = fmaxf(0.f, u1 - 1.f);

    const float* tb = sg + c0 * CSTR;
    const size_t obase = (size_t)b * NCO * HW + (size_t)y * NW + px0;

    #pragma unroll 1
    for (int co = 0; co < NCO; ++co) {
        float dA0, dA1, dB0, dB1, dC0, dC1;
        #pragma unroll
        for (int c = 0; c < 3; ++c) {
            const float* q = tb + c * CSTR + co * 16;
            const float4 a0 = *(const float4*)(q + 0);
            const float4 a1 = *(const float4*)(q + 4);
            const float4 a2 = *(const float4*)(q + 8);
            const float4 a3 = *(const float4*)(q + 12);
            float d0, d1;
            d0 = S0[0][0] * a0.x;              d1 = S0[1][0] * a0.x;
            d0 = fmaf(S0[0][1], a0.y, d0);     d1 = fmaf(S0[1][1], a0.y, d1);
            d0 = fmaf(S0[0][2], a0.z, d0);     d1 = fmaf(S0[1][2], a0.z, d1);
            d0 = fmaf(S0[0][3], a0.w, d0);     d1 = fmaf(S0[1][3], a0.w, d1);
            d0 = fmaf(S0[0][4], a1.x, d0);     d1 = fmaf(S0[1][4], a1.x, d1);
            d0 = fmaf(S0[0][5], a1.y, d0);     d1 = fmaf(S0[1][5], a1.y, d1);
            d0 = fmaf(S0[0][6], a1.z, d0);     d1 = fmaf(S0[1][6], a1.z, d1);
            d0 = fmaf(S0[0][7], a1.w, d0);     d1 = fmaf(S0[1][7], a1.w, d1);
            d0 = fmaf(S1[0][0], a2.x, d0);     d1 = fmaf(S1[1][0], a2.x, d1);
            d0 = fmaf(S1[0][1], a2.y, d0);     d1 = fmaf(S1[1][1], a2.y, d1);
            d0 = fmaf(S1[0][2], a2.z, d0);     d1 = fmaf(S1[1][2], a2.z, d1);
            d0 = fmaf(S1[0][3], a2.w, d0);     d1 = fmaf(S1[1][3], a2.w, d1);
            d0 = fmaf(S1[0][4], a3.x, d0);     d1 = fmaf(S1[1][4], a3.x, d1);
            d0 = fmaf(S1[0][5], a3.y, d0);     d1 = fmaf(S1[1][5], a3.y, d1);
            d0 = fmaf(S1[0][6], a3.z, d0);     d1 = fmaf(S1[1][6], a3.z, d1);
            d0 = fmaf(S1[0][7], a3.w, d0);     d1 = fmaf(S1[1][7], a3.w, d1);
            if (c == 0)      { dA0 = d0; dA1 = d1; }
            else if (c == 1) { dB0 = d0; dB1 = d1; }
            else             { dC0 = d0; dC1 = d1; }
        }
        float r0 = wA0 * dA0;
        r0 = fmaf(wB0, dB0, r0);
        r0 = fmaf(wC0, dC0, r0);
        float r1 = wA1 * dA1;
        r1 = fmaf(wB1, dB1, r1);
        r1 = fmaf(wC1, dC1, r1);
        *(float2*)(out + obase + (size_t)co * HW) = make_float2(r0, r1);
    }
}

extern "C" void kernel_launch(void* const* d_in, const int* in_sizes, int n_in,
                              void* d_out, int out_size, void* d_ws, size_t ws_size,
                              hipStream_t stream) {
    const float* grid  = (const float*)d_in[0];
    const float* guide = (const float*)d_in[1];
    const float* inp   = (const float*)d_in[2];
    float* out = (float*)d_out;

    dim3 g(NH, NB);   // (512 rows, 2 batches) = 1024 blocks x 4 waves = 4096 waves
    bslice_kernel<<<g, 256, 0, stream>>>(grid, guide, inp, out);
}